// Round 2
// baseline (395.467 us; speedup 1.0000x reference)
//
#include <hip/hip_runtime.h>

// NLinear: out[b,n,o] = sum_i x[b,n,i] * w[n,i,o] + bias[n,o]
// B=4096, N=200, D_IN=D_OUT=64.
//
// v3: fp16 split-MFMA (xh*wh + xh*wl + xl*wh ~= fp32-exact), with w
// pre-converted into per-lane MFMA B-fragments by a tiny prep kernel
// (workspace). Main kernel: no LDS, no barrier, 16 coalesced frag loads
// as the whole prologue, software-prefetched mf loop.
// v2 post-mortem: 148us with MfmaUtil 5% / VALU 15% / HBM 28% / occ 20%
// -> latency-bound on the per-block serial w-prep chain + short main loop.

#define B_DIM 4096
#define N_DIM 200
#define D 64
#define ROWS_PER_BLOCK 256

typedef __attribute__((ext_vector_type(8))) _Float16 half8;   // 4 VGPR
typedef __attribute__((ext_vector_type(4))) float f32x4;

__device__ __forceinline__ void split8(const float4 a, const float4 b,
                                       half8& h, half8& l) {
  const float f[8] = {a.x, a.y, a.z, a.w, b.x, b.y, b.z, b.w};
#pragma unroll
  for (int j = 0; j < 8; ++j) {
    const _Float16 hh = (_Float16)f[j];          // RNE
    h[j] = hh;
    l[j] = (_Float16)(f[j] - (float)hh);         // residual, ~2^-11 rel
  }
}

// ---- prep: w[n][k][col] -> split-fp16 per-lane B-fragments in workspace.
// Fragment (n, ks, nf): lane (kg=lane>>4, c=lane&15) holds
//   k = ks*32 + kg*8 + j, col = nf*16 + c, j = 0..7.
// Same (lane,j)->k map as the A side in the main kernel -> any consistent
// bijection of k sums identically in the MFMA.
__global__ __launch_bounds__(256)
void w_prep(const float* __restrict__ w,
            half8* __restrict__ wh, half8* __restrict__ wl) {
  const int n    = blockIdx.x;
  const int tid  = threadIdx.x;
  const int lane = tid & 63;
  const int g    = tid >> 6;
  const int c    = lane & 15;
  const int kg   = lane >> 4;
  const float* wn = w + (size_t)n * (D * D);
#pragma unroll
  for (int t = 0; t < 2; ++t) {
    const int combo = g * 2 + t;        // 0..7
    const int ks = combo >> 2;
    const int nf = combo & 3;
    half8 h, l;
#pragma unroll
    for (int j = 0; j < 8; ++j) {
      const int k = ks * 32 + kg * 8 + j;
      const float v = wn[k * D + nf * 16 + c];
      const _Float16 hh = (_Float16)v;
      h[j] = hh;
      l[j] = (_Float16)(v - (float)hh);
    }
    const size_t idx = ((size_t)(n * 2 + ks) * 4 + nf) * 64 + lane;
    wh[idx] = h;   // lane-contiguous 16B -> fully coalesced store/load
    wl[idx] = l;
  }
}

template <bool PREPPED>
__global__ __launch_bounds__(256, 4)
void nlinear_main(const float* __restrict__ x,
                  const float* __restrict__ w,
                  const float* __restrict__ bias,
                  const half8* __restrict__ wh,
                  const half8* __restrict__ wl,
                  float* __restrict__ out) {
  const int n    = blockIdx.y;
  const int tid  = threadIdx.x;
  const int lane = tid & 63;
  const int wave = tid >> 6;
  const int c    = lane & 15;   // A-row / B-col / D-col within fragment
  const int kg   = lane >> 4;   // k-group

  // Whole prologue: 16 coalesced dwordx4 loads (L2-hot, 3.3 MB total ws).
  half8 Wh[2][4], Wl[2][4];
  if (PREPPED) {
#pragma unroll
    for (int ks = 0; ks < 2; ++ks)
#pragma unroll
      for (int nf = 0; nf < 4; ++nf) {
        const size_t idx = ((size_t)(n * 2 + ks) * 4 + nf) * 64 + lane;
        Wh[ks][nf] = wh[idx];
        Wl[ks][nf] = wl[idx];
      }
  } else {
    // Fallback (workspace too small): gather + split from global w.
    const float* wn = w + (size_t)n * (D * D);
#pragma unroll
    for (int ks = 0; ks < 2; ++ks)
#pragma unroll
      for (int nf = 0; nf < 4; ++nf)
#pragma unroll
        for (int j = 0; j < 8; ++j) {
          const float v = wn[(ks * 32 + kg * 8 + j) * D + nf * 16 + c];
          const _Float16 hh = (_Float16)v;
          Wh[ks][nf][j] = hh;
          Wl[ks][nf][j] = (_Float16)(v - (float)hh);
        }
  }

  const float bv[4] = {bias[n * D + c],      bias[n * D + 16 + c],
                       bias[n * D + 32 + c], bias[n * D + 48 + c]};

  const size_t rstride = (size_t)N_DIM * D;          // 12800 floats
  const int row0 = blockIdx.x * ROWS_PER_BLOCK + wave * 64;
  const float* xb = x + (size_t)row0 * rstride + (size_t)n * D;
  float* ob = out + (size_t)row0 * rstride + (size_t)n * D;

  // Software pipeline: prefetch mf=0.
  const float* xr0 = xb + (size_t)c * rstride + kg * 8;
  float4 A0 = *(const float4*)(xr0);
  float4 A1 = *(const float4*)(xr0 + 4);
  float4 A2 = *(const float4*)(xr0 + 32);
  float4 A3 = *(const float4*)(xr0 + 36);

#pragma unroll 1
  for (int mf = 0; mf < 4; ++mf) {
    const float4 v0 = A0, v1 = A1, v2 = A2, v3 = A3;
    if (mf < 3) {
      const float* xn = xb + (size_t)((mf + 1) * 16 + c) * rstride + kg * 8;
      A0 = *(const float4*)(xn);
      A1 = *(const float4*)(xn + 4);
      A2 = *(const float4*)(xn + 32);
      A3 = *(const float4*)(xn + 36);
    }

    half8 ah[2], al[2];
    split8(v0, v1, ah[0], al[0]);   // k = kg*8 + j        (ks=0)
    split8(v2, v3, ah[1], al[1]);   // k = 32 + kg*8 + j   (ks=1)

    f32x4 acc[4];
#pragma unroll
    for (int nf = 0; nf < 4; ++nf) {
      f32x4 t = {bv[nf], bv[nf], bv[nf], bv[nf]};
      acc[nf] = t;
    }

#pragma unroll
    for (int ks = 0; ks < 2; ++ks)
#pragma unroll
      for (int nf = 0; nf < 4; ++nf) {
        acc[nf] = __builtin_amdgcn_mfma_f32_16x16x32_f16(ah[ks], Wh[ks][nf], acc[nf], 0, 0, 0);
        acc[nf] = __builtin_amdgcn_mfma_f32_16x16x32_f16(ah[ks], Wl[ks][nf], acc[nf], 0, 0, 0);
        acc[nf] = __builtin_amdgcn_mfma_f32_16x16x32_f16(al[ks], Wh[ks][nf], acc[nf], 0, 0, 0);
      }

    // D map (verified): col = lane&15, row = (lane>>4)*4 + j.
    float* orow = ob + (size_t)(mf * 16 + kg * 4) * rstride;
#pragma unroll
    for (int nf = 0; nf < 4; ++nf)
#pragma unroll
      for (int j = 0; j < 4; ++j)
        orow[(size_t)j * rstride + nf * 16 + c] = acc[nf][j];
  }
}

extern "C" void kernel_launch(void* const* d_in, const int* in_sizes, int n_in,
                              void* d_out, int out_size, void* d_ws, size_t ws_size,
                              hipStream_t stream) {
  const float* x    = (const float*)d_in[0];   // (4096, 200, 64)
  const float* w    = (const float*)d_in[1];   // (1, 200, 64, 64)
  const float* bias = (const float*)d_in[2];   // (1, 200, 64)
  float*       out  = (float*)d_out;           // (4096, 200, 64)

  const size_t NFRAGS = (size_t)N_DIM * 2 * 4 * 64;      // 102400 fragments
  const size_t NEED   = NFRAGS * 16 * 2;                 // 3,276,800 B

  dim3 grid(B_DIM / ROWS_PER_BLOCK, N_DIM);              // 16 x 200
  if (d_ws && ws_size >= NEED) {
    half8* wh = (half8*)d_ws;
    half8* wl = wh + NFRAGS;
    w_prep<<<dim3(N_DIM), dim3(256), 0, stream>>>(w, wh, wl);
    nlinear_main<true><<<grid, dim3(256), 0, stream>>>(x, w, bias, wh, wl, out);
  } else {
    nlinear_main<false><<<grid, dim3(256), 0, stream>>>(x, w, bias, nullptr, nullptr, out);
  }
}

// Round 3
// 377.295 us; speedup vs baseline: 1.0482x; 1.0482x over previous
//
#include <hip/hip_runtime.h>

// NLinear: out[b,n,o] = sum_i x[b,n,i] * w[n,i,o] + bias[n,o]
// B=4096, N=200, D_IN=D_OUT=64.
//
// v4: operand-swapped MFMA (D^T layout) -> float4 stores.
// v3 post-mortem: 148us, all pipes idle (Mfma 5, VALU 6, HBM 35%), occupancy
// 37% -> stalled on the vector-memory path. 64 scattered store_dword per wave
// (4B/lane-row segments) saturate TA + vmcnt queue. Swapping mfma(W,x) makes
// each lane hold 4 consecutive o-values -> 16 store_dwordx4 per wave with 64B
// row segments. x fragments and prepped W fragments are UNCHANGED (A/B lane->k
// maps are the same function; proven by v2/v3 passing).

#define B_DIM 4096
#define N_DIM 200
#define D 64
#define ROWS_PER_BLOCK 256

typedef __attribute__((ext_vector_type(8))) _Float16 half8;   // 4 VGPR
typedef __attribute__((ext_vector_type(4))) float f32x4;

__device__ __forceinline__ void split8(const float4 a, const float4 b,
                                       half8& h, half8& l) {
  const float f[8] = {a.x, a.y, a.z, a.w, b.x, b.y, b.z, b.w};
#pragma unroll
  for (int j = 0; j < 8; ++j) {
    const _Float16 hh = (_Float16)f[j];          // RNE
    h[j] = hh;
    l[j] = (_Float16)(f[j] - (float)hh);         // residual, ~2^-11 rel
  }
}

// prep: w[n][k][o] -> split-fp16 per-lane fragments.
// Fragment (n, ks, of): lane (kg=lane>>4, c=lane&15), j=0..7 holds
// w[ks*32+kg*8+j][of*16+c].  Used as the MFMA *A* operand:
// A[row=c][k=kg*8+j] = W'[o=of*16+c][k]  (W' = w^T).
__global__ __launch_bounds__(256)
void w_prep(const float* __restrict__ w,
            half8* __restrict__ wh, half8* __restrict__ wl) {
  const int n    = blockIdx.x;
  const int tid  = threadIdx.x;
  const int lane = tid & 63;
  const int g    = tid >> 6;
  const int c    = lane & 15;
  const int kg   = lane >> 4;
  const float* wn = w + (size_t)n * (D * D);
#pragma unroll
  for (int t = 0; t < 2; ++t) {
    const int combo = g * 2 + t;        // 0..7
    const int ks = combo >> 2;
    const int of = combo & 3;
    half8 h, l;
#pragma unroll
    for (int j = 0; j < 8; ++j) {
      const int k = ks * 32 + kg * 8 + j;
      const float v = wn[k * D + of * 16 + c];
      const _Float16 hh = (_Float16)v;
      h[j] = hh;
      l[j] = (_Float16)(v - (float)hh);
    }
    const size_t idx = ((size_t)(n * 2 + ks) * 4 + of) * 64 + lane;
    wh[idx] = h;   // lane-contiguous 16B -> fully coalesced
    wl[idx] = l;
  }
}

template <bool PREPPED>
__global__ __launch_bounds__(256, 3)
void nlinear_main(const float* __restrict__ x,
                  const float* __restrict__ w,
                  const float* __restrict__ bias,
                  const half8* __restrict__ wh,
                  const half8* __restrict__ wl,
                  float* __restrict__ out) {
  const int n    = blockIdx.y;
  const int tid  = threadIdx.x;
  const int lane = tid & 63;
  const int wave = tid >> 6;
  const int c    = lane & 15;   // b-row within 16 (B-col / D-col)
  const int kg   = lane >> 4;   // k-group

  // W fragments (A-operand): 16 coalesced dwordx4, L2-hot (3.3 MB ws).
  half8 Wh[2][4], Wl[2][4];
  if (PREPPED) {
#pragma unroll
    for (int ks = 0; ks < 2; ++ks)
#pragma unroll
      for (int of = 0; of < 4; ++of) {
        const size_t idx = ((size_t)(n * 2 + ks) * 4 + of) * 64 + lane;
        Wh[ks][of] = wh[idx];
        Wl[ks][of] = wl[idx];
      }
  } else {
    const float* wn = w + (size_t)n * (D * D);
#pragma unroll
    for (int ks = 0; ks < 2; ++ks)
#pragma unroll
      for (int of = 0; of < 4; ++of)
#pragma unroll
        for (int j = 0; j < 8; ++j) {
          const float v = wn[(ks * 32 + kg * 8 + j) * D + of * 16 + c];
          const _Float16 hh = (_Float16)v;
          Wh[ks][of][j] = hh;
          Wl[ks][of][j] = (_Float16)(v - (float)hh);
        }
  }

  // Bias: D^T map gives lane (c,kg) the outputs o = of*16 + kg*4 + {0..3}.
  float4 bv4[4];
#pragma unroll
  for (int of = 0; of < 4; ++of)
    bv4[of] = *(const float4*)(bias + (size_t)n * D + of * 16 + kg * 4);

  const size_t rstride = (size_t)N_DIM * D;          // 12800 floats
  const int row0 = blockIdx.x * ROWS_PER_BLOCK + wave * 64;
  const float* xb = x + (size_t)row0 * rstride + (size_t)n * D;
  float* ob = out + (size_t)row0 * rstride + (size_t)n * D;

  // x fragment addresses: B-operand, lane holds x[row=mf*16+c][k=kg*8+j(+32)].
  auto xaddr = [&](int mf) {
    return xb + (size_t)(mf * 16 + c) * rstride + kg * 8;
  };

  // 2-deep VGPR double-buffer prefetch.
  float4 P[2][4];
  {
    const float* p0 = xaddr(0);
    P[0][0] = *(const float4*)(p0);
    P[0][1] = *(const float4*)(p0 + 4);
    P[0][2] = *(const float4*)(p0 + 32);
    P[0][3] = *(const float4*)(p0 + 36);
    const float* p1 = xaddr(1);
    P[1][0] = *(const float4*)(p1);
    P[1][1] = *(const float4*)(p1 + 4);
    P[1][2] = *(const float4*)(p1 + 32);
    P[1][3] = *(const float4*)(p1 + 36);
  }

#pragma unroll
  for (int mf = 0; mf < 4; ++mf) {
    const int buf = mf & 1;                 // static after unroll
    const float4 v0 = P[buf][0], v1 = P[buf][1];
    const float4 v2 = P[buf][2], v3 = P[buf][3];
    if (mf < 2) {
      const float* pn = xaddr(mf + 2);
      P[buf][0] = *(const float4*)(pn);
      P[buf][1] = *(const float4*)(pn + 4);
      P[buf][2] = *(const float4*)(pn + 32);
      P[buf][3] = *(const float4*)(pn + 36);
    }

    half8 ah0, al0, ah1, al1;
    split8(v0, v1, ah0, al0);   // ks=0: k = kg*8+j
    split8(v2, v3, ah1, al1);   // ks=1: k = 32+kg*8+j

    f32x4 acc[4];
#pragma unroll
    for (int of = 0; of < 4; ++of) {
      f32x4 t = {bv4[of].x, bv4[of].y, bv4[of].z, bv4[of].w};
      acc[of] = t;
    }

#pragma unroll
    for (int of = 0; of < 4; ++of) {
      acc[of] = __builtin_amdgcn_mfma_f32_16x16x32_f16(Wh[0][of], ah0, acc[of], 0, 0, 0);
      acc[of] = __builtin_amdgcn_mfma_f32_16x16x32_f16(Wl[0][of], ah0, acc[of], 0, 0, 0);
      acc[of] = __builtin_amdgcn_mfma_f32_16x16x32_f16(Wh[0][of], al0, acc[of], 0, 0, 0);
      acc[of] = __builtin_amdgcn_mfma_f32_16x16x32_f16(Wh[1][of], ah1, acc[of], 0, 0, 0);
      acc[of] = __builtin_amdgcn_mfma_f32_16x16x32_f16(Wl[1][of], ah1, acc[of], 0, 0, 0);
      acc[of] = __builtin_amdgcn_mfma_f32_16x16x32_f16(Wh[1][of], al1, acc[of], 0, 0, 0);
    }

    // D^T map: lane (c,kg) holds out[b=mf*16+c][o=of*16+kg*4+jj], jj=0..3
    // -> one float4 store per of; per instr 16 rows x 64B contiguous.
    float* orow = ob + (size_t)(mf * 16 + c) * rstride;
#pragma unroll
    for (int of = 0; of < 4; ++of)
      *(f32x4*)(orow + of * 16 + kg * 4) = acc[of];
  }
}

extern "C" void kernel_launch(void* const* d_in, const int* in_sizes, int n_in,
                              void* d_out, int out_size, void* d_ws, size_t ws_size,
                              hipStream_t stream) {
  const float* x    = (const float*)d_in[0];   // (4096, 200, 64)
  const float* w    = (const float*)d_in[1];   // (1, 200, 64, 64)
  const float* bias = (const float*)d_in[2];   // (1, 200, 64)
  float*       out  = (float*)d_out;           // (4096, 200, 64)

  const size_t NFRAGS = (size_t)N_DIM * 2 * 4 * 64;      // 102400 fragments
  const size_t NEED   = NFRAGS * 16 * 2;                 // 3,276,800 B

  dim3 grid(B_DIM / ROWS_PER_BLOCK, N_DIM);              // 16 x 200
  if (d_ws && ws_size >= NEED) {
    half8* whp = (half8*)d_ws;
    half8* wlp = whp + NFRAGS;
    w_prep<<<dim3(N_DIM), dim3(256), 0, stream>>>(w, whp, wlp);
    nlinear_main<true><<<grid, dim3(256), 0, stream>>>(x, w, bias, whp, wlp, out);
  } else {
    nlinear_main<false><<<grid, dim3(256), 0, stream>>>(x, w, bias, nullptr, nullptr, out);
  }
}